// Round 5
// baseline (949.272 us; speedup 1.0000x reference)
//
#include <hip/hip_runtime.h>

typedef _Float16 f16x8 __attribute__((ext_vector_type(8)));
typedef float    f32x4 __attribute__((ext_vector_type(4)));

#define NROWS   262144
#define DIN     128
#define DOUT    256
#define CHUNKS  4                     // chunks per persistent block
#define MBLOCKS (NROWS / (CHUNKS * 128))   // 512 blocks, 512 thr, 128 rows/chunk
#define NCHUNKS (NROWS / 64)          // fallback grid constant
#define WS_NEED (DIN * DOUT * 2 + DOUT * 4)   // W' fp16 + b2 table

#define SWZ_F(x, pat) __int_as_float(__builtin_amdgcn_ds_swizzle(__float_as_int(x), (pat)))
#define SWZ_I(x, pat) __builtin_amdgcn_ds_swizzle((x), (pat))
#define SWZ_X16 0x401F   // bitmode xor-16: lane <-> lane^16 (within 32-lane half)

// ---------- prep: W' = W * gamma/rsqrt(var+eps) in fp16 B-frag order; b2 table ----------
__global__ void prep_kernel(const float* __restrict__ W,
                            const float* __restrict__ gamma,
                            const float* __restrict__ beta,
                            const float* __restrict__ mmean,
                            const float* __restrict__ mvar,
                            _Float16* __restrict__ wq,
                            float* __restrict__ b2tab)
{
    const int tid  = blockIdx.x * 256 + threadIdx.x;    // 0..4095 = (t, q, lane)
    const int t    = tid >> 8;
    const int q    = (tid >> 6) & 3;
    const int lane = tid & 63;
    const int n    = 16 * t + (lane & 15);
    const int k0   = 32 * q + 8 * (lane >> 4);
    const float inv = gamma[n] / sqrtf(mvar[n] + 1e-3f);
    f16x8 v;
    #pragma unroll
    for (int j = 0; j < 8; ++j)
        v[j] = (_Float16)(W[(k0 + j) * DOUT + n] * inv);
    *(f16x8*)(wq + (size_t)tid * 8) = v;               // frag half-index = ((t*4+q)*64+lane)*8+j
    if (blockIdx.x == 0) {
        const int c = threadIdx.x;
        const float invc = gamma[c] / sqrtf(mvar[c] + 1e-3f);
        b2tab[c] = beta[c] - mmean[c] * invc;
    }
}

// ---------- main ----------
// Round-5: latency-structure rewrite (R3/R4 showed neither TLP nor VALU work is
// binding; the serial barrier-locked phase chain left the memory pipe ~45%
// utilized).
//  * Operand-swapped MFMA: mfma(bf, af, acc) -> C-layout col(lane&15)=batch
//    row, reg=dout. Each lane holds one row's 64 z-values in 4-col runs ->
//    NO LDS transpose, NO second barrier, z stays in registers.
//  * Persistent blocks (512 blocks x 512 thr x 4 chunks), wq+b2 staged once;
//    after the prologue barrier the loop is barrier-free: each wave pipelines
//    independently (A_{c+1} + priors_{c+1} issued under solve_c).
//  * BN fused into the GEMM t-loop; priors streamed in quarters so register
//    peak stays under the 128 cap of __launch_bounds__(512,4).
// Michelot: row = 4 lanes {r, r+16, r+32, r+48}; reduce = ds_swizzle xor16 +
// __shfl_xor 32. Warm start tau0 = rowmax-1 (provably <= tau*; K>=1 so
// kprev=0 safe).
__global__ __launch_bounds__(512, 4)
void attentive_main(const float* __restrict__ A,
                    const float* __restrict__ priors,
                    const _Float16* __restrict__ wq,
                    const float* __restrict__ b2tab,
                    float* __restrict__ out)
{
    __shared__ _Float16 wq_lds[DIN * DOUT];   // 64 KiB, read-only after prologue
    __shared__ float    b2_lds[DOUT];         // 1 KiB

    const int tid  = threadIdx.x;
    const int lane = tid & 63;
    const int wv   = tid >> 6;             // 0..7
    const int nl   = lane & 15;            // batch row within wave tile (C col)
    const int quad = lane >> 4;            // dout sub-block (C rows 4*quad+j)

    // ---- prologue: stage W' (64 KiB) + b2 into LDS ----
    {
        const char* gsrc = (const char*)wq + wv * 1024 + lane * 16;
        #pragma unroll
        for (int r = 0; r < 8; ++r) {
            __builtin_amdgcn_global_load_lds(
                (const __attribute__((address_space(1))) void*)(gsrc + r * 8192),
                (__attribute__((address_space(3))) void*)((char*)wq_lds + wv * 1024 + r * 8192),
                16, 0, 0);
        }
        if (tid < DOUT) b2_lds[tid] = b2tab[tid];
    }

    // ---- issue chunk-0 A rows + priors quarter-A (latency hidden by staging) ----
    const int row0 = blockIdx.x * (CHUNKS * 128) + wv * 16 + nl;
    f32x4 a0[8];                           // A row fp32 (32 VGPR), loop-carried
    f32x4 pA[4];                           // priors t=0..3 (16 VGPR), loop-carried
    {
        const float* arow = A + (size_t)row0 * DIN + (quad << 3);
        #pragma unroll
        for (int q = 0; q < 4; ++q) {
            a0[2 * q]     = *(const f32x4*)(arow + (q << 5));
            a0[2 * q + 1] = *(const f32x4*)(arow + (q << 5) + 4);
        }
        const float* prow = priors + (size_t)row0 * DOUT + (quad << 2);
        #pragma unroll
        for (int k = 0; k < 4; ++k)
            pA[k] = __builtin_nontemporal_load((const f32x4*)(prow + (k << 4)));
    }

    __syncthreads();   // wq_lds + b2_lds valid; only barrier in the kernel

    #pragma unroll 1
    for (int c = 0; c < CHUNKS; ++c) {
        const int row = row0 + c * 128;    // this lane's batch row

        // ---- cvt A fp32 -> fp16 fragments (af[q][j] = A[row][32q+8quad+j]) ----
        f16x8 af[4];
        #pragma unroll
        for (int q = 0; q < 4; ++q) {
            const f32x4 vlo = a0[2 * q], vhi = a0[2 * q + 1];
            f16x8 v;
            v[0] = (_Float16)vlo[0]; v[1] = (_Float16)vlo[1];
            v[2] = (_Float16)vlo[2]; v[3] = (_Float16)vlo[3];
            v[4] = (_Float16)vhi[0]; v[5] = (_Float16)vhi[1];
            v[6] = (_Float16)vhi[2]; v[7] = (_Float16)vhi[3];
            af[q] = v;
        }

        const float* prowc = priors + (size_t)row * DOUT + (quad << 2);
        f32x4 pB[4];
        #pragma unroll
        for (int k = 0; k < 4; ++k)
            pB[k] = __builtin_nontemporal_load((const f32x4*)(prowc + ((k + 4) << 4)));

        // ---- GEMM (swapped operands) with fused BN + prior + row-max ----
        // z[t][j] = z[row][dout = 16t + 4*quad + j]
        f32x4 z[16];
        f32x4 pC[4], pD[4];
        float m = -3.0e38f;
        #pragma unroll
        for (int t = 0; t < 16; ++t) {
            f32x4 cacc = {0.f, 0.f, 0.f, 0.f};
            #pragma unroll
            for (int q = 0; q < 4; ++q) {
                const f16x8 bf = *(const f16x8*)&wq_lds[((((t << 2) + q) << 6) + lane) << 3];
                cacc = __builtin_amdgcn_mfma_f32_16x16x32_f16(bf, af[q], cacc, 0, 0, 0);
            }
            if (t == 2) {
                #pragma unroll
                for (int k = 0; k < 4; ++k)
                    pC[k] = __builtin_nontemporal_load((const f32x4*)(prowc + ((k + 8) << 4)));
            }
            if (t == 6) {
                #pragma unroll
                for (int k = 0; k < 4; ++k)
                    pD[k] = __builtin_nontemporal_load((const f32x4*)(prowc + ((k + 12) << 4)));
            }
            const f32x4 b2v = *(const f32x4*)&b2_lds[(t << 4) + (quad << 2)];
            const f32x4 pv  = (t < 4) ? pA[t] : (t < 8) ? pB[t - 4]
                             : (t < 12) ? pC[t - 8] : pD[t - 12];
            f32x4 zz;
            #pragma unroll
            for (int j = 0; j < 4; ++j) {
                zz[j] = (cacc[j] + b2v[j]) * pv[j];
                m = fmaxf(m, zz[j]);
            }
            z[t] = zz;
        }

        // ---- row max over the 4 lanes sharing this row (^16, ^32) ----
        m = fmaxf(m, SWZ_F(m, SWZ_X16));
        m = fmaxf(m, __shfl_xor(m, 32));

        // ---- issue next chunk's A + priors-A (hidden under michelot+stores) ----
        if (c + 1 < CHUNKS) {
            const float* arow2 = A + (size_t)(row + 128) * DIN + (quad << 3);
            #pragma unroll
            for (int q = 0; q < 4; ++q) {
                a0[2 * q]     = *(const f32x4*)(arow2 + (q << 5));
                a0[2 * q + 1] = *(const f32x4*)(arow2 + (q << 5) + 4);
            }
            const float* prow2 = priors + (size_t)(row + 128) * DOUT + (quad << 2);
            #pragma unroll
            for (int k = 0; k < 4; ++k)
                pA[k] = __builtin_nontemporal_load((const f32x4*)(prow2 + (k << 4)));
        }

        // ---- Michelot, warm start tau0 = m-1; 64 elems/lane, 4-lane reduce ----
        float tau = m - 1.0f, kprev = 0.0f;
        for (int it = 0; it < 64; ++it) {
            float Sa = 0.f, Sb = 0.f, Ka = 0.f, Kb = 0.f;
            #pragma unroll
            for (int t = 0; t < 16; t += 2) {
                #pragma unroll
                for (int j = 0; j < 4; ++j) {
                    const float z0 = z[t][j], z1 = z[t + 1][j];
                    const bool b0 = z0 > tau, b1 = z1 > tau;
                    Sa += b0 ? z0 : 0.0f;  Ka += b0 ? 1.0f : 0.0f;
                    Sb += b1 ? z1 : 0.0f;  Kb += b1 ? 1.0f : 0.0f;
                }
            }
            float S = Sa + Sb, K = Ka + Kb;
            S += SWZ_F(S, SWZ_X16);  K += SWZ_F(K, SWZ_X16);
            S += __shfl_xor(S, 32);  K += __shfl_xor(K, 32);
            tau = (S - 1.0f) * __builtin_amdgcn_rcpf(K);
            const bool conv = (K == kprev);
            kprev = K;
            if (__all(conv)) break;
        }

        // ---- stores: 16 x f32x4 NT, 64B-coalesced per row segment ----
        float* orow = out + (size_t)row * DOUT + (quad << 2);
        #pragma unroll
        for (int t = 0; t < 16; ++t) {
            f32x4 o;
            #pragma unroll
            for (int j = 0; j < 4; ++j)
                o[j] = fmaxf(z[t][j] - tau, 0.0f);
            __builtin_nontemporal_store(o, (f32x4*)(orow + (t << 4)));
        }
    }
}

// ---------- fallback (round-1 kernel, proven correct) for tiny ws ----------
__global__ __launch_bounds__(256, 2)
void attentive_fallback(const float* __restrict__ A,
                        const float* __restrict__ priors,
                        const float* __restrict__ W,
                        const float* __restrict__ gamma,
                        const float* __restrict__ beta,
                        const float* __restrict__ mmean,
                        const float* __restrict__ mvar,
                        float* __restrict__ out)
{
    __shared__ _Float16 wlds[DIN * DOUT];
    const int tid = threadIdx.x;
    {
        const int n = tid;
        const float inv = gamma[n] / sqrtf(mvar[n] + 1e-3f);
        const int t = n >> 4, nl0 = n & 15;
        #pragma unroll 8
        for (int k = 0; k < DIN; ++k) {
            const int q = k >> 5, qd = (k >> 3) & 3, j = k & 7;
            const int idx = (((((t << 2) + q) << 6) + (qd << 4) + nl0) << 3) + j;
            wlds[idx] = (_Float16)(W[k * DOUT + n] * inv);
        }
    }
    __syncthreads();

    const int lane = tid & 63, wv = tid >> 6;
    const int nl = lane & 15, quad = lane >> 4;

    float b2r[16];
    #pragma unroll
    for (int t = 0; t < 16; ++t) {
        const int c = (t << 4) + nl;
        const float inv = gamma[c] / sqrtf(mvar[c] + 1e-3f);
        b2r[t] = beta[c] - mmean[c] * inv;
    }

    for (int chunk = blockIdx.x; chunk < NCHUNKS; chunk += gridDim.x) {
        const int r0 = chunk * 64 + wv * 16;
        f16x8 af[4];
        const float* arow = A + (size_t)(r0 + nl) * DIN + (quad << 3);
        #pragma unroll
        for (int q = 0; q < 4; ++q) {
            const f32x4 vlo = *(const f32x4*)(arow + (q << 5));
            const f32x4 vhi = *(const f32x4*)(arow + (q << 5) + 4);
            f16x8 v;
            v[0] = (_Float16)vlo[0]; v[1] = (_Float16)vlo[1];
            v[2] = (_Float16)vlo[2]; v[3] = (_Float16)vlo[3];
            v[4] = (_Float16)vhi[0]; v[5] = (_Float16)vhi[1];
            v[6] = (_Float16)vhi[2]; v[7] = (_Float16)vhi[3];
            af[q] = v;
        }
        f32x4 acc[16];
        #pragma unroll
        for (int t = 0; t < 16; ++t) {
            f32x4 c = {0.f, 0.f, 0.f, 0.f};
            #pragma unroll
            for (int q = 0; q < 4; ++q) {
                const f16x8 bf = *(const f16x8*)&wlds[((((t << 2) + q) << 6) + lane) << 3];
                c = __builtin_amdgcn_mfma_f32_16x16x32_f16(af[q], bf, c, 0, 0, 0);
            }
            acc[t] = c;
        }
        const int rb = r0 + (quad << 2);
        #pragma unroll
        for (int t = 0; t < 16; ++t) {
            const int c = (t << 4) + nl;
            #pragma unroll
            for (int j = 0; j < 4; ++j) {
                const float p = priors[(size_t)(rb + j) * DOUT + c];
                acc[t][j] = (acc[t][j] + b2r[t]) * p;
            }
        }
        float tau[4] = {-3.0e38f, -3.0e38f, -3.0e38f, -3.0e38f};
        int   kp[4]  = {-1, -1, -1, -1};
        for (int it = 0; it < 64; ++it) {
            float S[4] = {0.f, 0.f, 0.f, 0.f};
            int   K[4] = {0, 0, 0, 0};
            #pragma unroll
            for (int t = 0; t < 16; ++t) {
                #pragma unroll
                for (int j = 0; j < 4; ++j) {
                    const float z = acc[t][j];
                    const bool b = z > tau[j];
                    S[j] += b ? z : 0.0f;
                    K[j] += b ? 1 : 0;
                }
            }
            #pragma unroll
            for (int j = 0; j < 4; ++j) {
                S[j] += SWZ_F(S[j], 0x041F); K[j] += SWZ_I(K[j], 0x041F);
                S[j] += SWZ_F(S[j], 0x081F); K[j] += SWZ_I(K[j], 0x081F);
                S[j] += SWZ_F(S[j], 0x101F); K[j] += SWZ_I(K[j], 0x101F);
                S[j] += SWZ_F(S[j], 0x201F); K[j] += SWZ_I(K[j], 0x201F);
            }
            bool conv = true;
            #pragma unroll
            for (int j = 0; j < 4; ++j) {
                tau[j] = (S[j] - 1.0f) * __builtin_amdgcn_rcpf((float)K[j]);
                conv = conv && (K[j] == kp[j]);
                kp[j] = K[j];
            }
            if (__all(conv)) break;
        }
        #pragma unroll
        for (int t = 0; t < 16; ++t) {
            const int c = (t << 4) + nl;
            #pragma unroll
            for (int j = 0; j < 4; ++j)
                out[(size_t)(rb + j) * DOUT + c] = fmaxf(acc[t][j] - tau[j], 0.0f);
        }
    }
}

extern "C" void kernel_launch(void* const* d_in, const int* in_sizes, int n_in,
                              void* d_out, int out_size, void* d_ws, size_t ws_size,
                              hipStream_t stream) {
    const float* inputs = (const float*)d_in[0];
    const float* priors = (const float*)d_in[1];
    const float* W      = (const float*)d_in[2];
    const float* gam    = (const float*)d_in[3];
    const float* bet    = (const float*)d_in[4];
    const float* mmean  = (const float*)d_in[5];
    const float* mvar   = (const float*)d_in[6];
    float* outp = (float*)d_out;
    (void)in_sizes; (void)n_in; (void)out_size;

    if (ws_size >= (size_t)WS_NEED) {
        _Float16* wq    = (_Float16*)d_ws;
        float*    b2tab = (float*)((char*)d_ws + DIN * DOUT * 2);
        hipLaunchKernelGGL(prep_kernel, dim3(16), dim3(256), 0, stream,
                           W, gam, bet, mmean, mvar, wq, b2tab);
        hipLaunchKernelGGL(attentive_main, dim3(MBLOCKS), dim3(512), 0, stream,
                           inputs, priors, wq, b2tab, outp);
    } else {
        hipLaunchKernelGGL(attentive_fallback, dim3(1024), dim3(256), 0, stream,
                           inputs, priors, W, gam, bet, mmean, mvar, outp);
    }
}